// Round 1
// 221.523 us; speedup vs baseline: 1.0325x; 1.0325x over previous
//
#include <hip/hip_runtime.h>
#include <hip/hip_fp16.h>

#define NN 80000
#define NE 1280000
#define F  64
#define BSH 9                        // 512 nodes per bucket
#define NB  157                      // ceil(NN / 512)
#define CAP 12288                    // per-bucket ebuf capacity (avg 8153)
#define EPB 5120                     // edges per partition block (128 B runs)
#define EPT 10                       // EPB / 512
#define PBLK (NE / EPB)              // 250

typedef _Float16 half_t;
typedef _Float16 half8 __attribute__((ext_vector_type(8)));
typedef float f32x4 __attribute__((ext_vector_type(4)));
typedef unsigned int uint_t;

__device__ __forceinline__ float2 h2f2(uint_t u) {
    __half2 h = *(__half2*)&u;
    return __half22float2(h);
}

__device__ __forceinline__ int ld_src(const int* __restrict__ idx, int e, int is64) {
    return is64 ? idx[2 * e] : idx[e];
}
__device__ __forceinline__ int ld_dst(const int* __restrict__ idx, int e, int is64) {
    return is64 ? idx[2 * NE + 2 * e] : idx[NE + e];
}

// ---------------------------------------------------------------------------
// Pass 1 (512 threads): partition edges into NB dst-buckets via LDS staging
// (cache-granular global writes, ~32-edge/128 B runs).
// ebuf[b*CAP + j] = (dstoff<<17) | src. Inline int64-vs-int32 sniff.
// ---------------------------------------------------------------------------
__global__ __launch_bounds__(512) void partition_kernel(
        const int* __restrict__ idx,
        int* __restrict__ bcur, int* __restrict__ ebuf) {
    __shared__ int cnt[NB];
    __shared__ int lbase[NB];
    __shared__ int gbase[NB];
    __shared__ int lds_val[EPB];
    __shared__ int lds_gaddr[EPB];
    __shared__ int is64_s;
    int tid = threadIdx.x;
    if (tid == 0) is64_s = 1;
    if (tid < NB) cnt[tid] = 0;
    __syncthreads();
    if (idx[2 * tid + 1] != 0) is64_s = 0;   // benign same-value race
    __syncthreads();
    int is64 = is64_s;
    int e0 = blockIdx.x * EPB;
    int val[EPT], br[EPT];
    #pragma unroll
    for (int j = 0; j < EPT; ++j) {
        int e = e0 + j * 512 + tid;
        int s = ld_src(idx, e, is64);
        int d = ld_dst(idx, e, is64);
        int b = d >> BSH;
        val[j] = ((d & ((1 << BSH) - 1)) << 17) | s;
        int r = atomicAdd(&cnt[b], 1);       // rank within (block, bucket)
        br[j] = (b << 13) | r;               // r < 5120 < 2^13
    }
    __syncthreads();
    if (tid < 64) {
        int carry = 0;
        for (int base = 0; base < NB; base += 64) {
            int i2 = base + tid;
            int v = (i2 < NB) ? cnt[i2] : 0;
            int incl = v;
            #pragma unroll
            for (int d2 = 1; d2 < 64; d2 <<= 1) {
                int t = __shfl_up(incl, d2, 64);
                if (tid >= d2) incl += t;
            }
            if (i2 < NB) lbase[i2] = carry + incl - v;
            carry += __shfl(incl, 63);
        }
    } else if (tid - 64 < NB) {
        int b = tid - 64;
        gbase[b] = atomicAdd(&bcur[b], cnt[b]);
    }
    __syncthreads();
    #pragma unroll
    for (int j = 0; j < EPT; ++j) {
        int b = br[j] >> 13, r = br[j] & 8191;
        int slot = lbase[b] + r;
        int g = gbase[b] + r;
        lds_val[slot]   = val[j];
        lds_gaddr[slot] = (g < CAP) ? (b * CAP + g) : -1;   // overflow guard
    }
    __syncthreads();
    for (int i = tid; i < EPB; i += 512) {
        int a = lds_gaddr[i];
        if (a >= 0) ebuf[a] = lds_val[i];    // ~32-edge (128 B) contiguous runs
    }
}

// ---------------------------------------------------------------------------
// Pass 2 (1024 threads): per-bucket LDS counting sort -> final CSR edata +
// row_ptr + dinv. NEW: prescale folded in (y0 = fp16(X * dinv), using the
// in-LDS degree counters) — removes the standalone prescale kernel.
// ---------------------------------------------------------------------------
__global__ __launch_bounds__(1024) void bucket_sort_kernel(
        const int* __restrict__ bcur, const int* __restrict__ ebuf,
        const float* __restrict__ X,
        int* __restrict__ edata, int* __restrict__ row_ptr,
        float* __restrict__ dinv, half_t* __restrict__ y0) {
    __shared__ int cnt[512];
    __shared__ int off[512];
    __shared__ int lds_out[CAP];
    __shared__ int ebase_s;
    int b = blockIdx.x, tid = threadIdx.x;
    if (tid < 512) cnt[tid] = 0;
    if (tid < 64) {        // ebase = sum of min(bcur[j],CAP) for j<b
        int carry = 0;
        for (int base = 0; base < NB; base += 64) {
            int i2 = base + tid;
            int v = (i2 < NB) ? min(bcur[i2], CAP) : 0;
            int incl = v;
            #pragma unroll
            for (int d2 = 1; d2 < 64; d2 <<= 1) {
                int t = __shfl_up(incl, d2, 64);
                if (tid >= d2) incl += t;
            }
            if (i2 == b) ebase_s = carry + incl - v;
            carry += __shfl(incl, 63);
        }
    }
    __syncthreads();
    int bcnt = min(bcur[b], CAP);
    int ebase = ebase_s;
    const int* src = ebuf + b * CAP;
    for (int i = tid; i < bcnt; i += 1024)
        atomicAdd(&cnt[src[i] >> 17], 1);
    __syncthreads();
    if (tid < 64) {        // exclusive scan of 512 counters
        int carry = 0;
        #pragma unroll
        for (int base = 0; base < 512; base += 64) {
            int v = cnt[base + tid];
            int incl = v;
            #pragma unroll
            for (int d2 = 1; d2 < 64; d2 <<= 1) {
                int t = __shfl_up(incl, d2, 64);
                if (tid >= d2) incl += t;
            }
            off[base + tid] = carry + incl - v;
            carry += __shfl(incl, 63);
        }
    }
    __syncthreads();
    int n0 = b << BSH;
    if (tid < 512) {
        int n = n0 + tid;
        if (n < NN) {
            row_ptr[n] = ebase + off[tid];
            dinv[n] = rsqrtf((float)cnt[tid] + 1.f);
        } else if (n == NN) {
            row_ptr[NN] = ebase + off[tid];
        }
    }
    __syncthreads();
    for (int i = tid; i < bcnt; i += 1024) {
        int w = src[i];
        int pos = atomicAdd(&off[w >> 17], 1);
        lds_out[pos] = w & 0x1FFFF;
    }
    __syncthreads();
    for (int i = tid; i < bcnt; i += 1024)
        edata[ebase + i] = lds_out[i];
    // folded prescale: y0 = fp16(X * dinv) for this bucket's 512 rows.
    // cnt[] is final since the counting barrier and never overwritten.
    for (int i = tid; i < (512 << 4); i += 1024) {
        int r = i >> 4, qq = i & 15;
        int n = n0 + r;
        if (n < NN) {
            float c = rsqrtf((float)cnt[r] + 1.f);
            float4 v = ((const float4*)(X + (size_t)n * F))[qq];
            half_t h[4] = { (half_t)(v.x * c), (half_t)(v.y * c),
                            (half_t)(v.z * c), (half_t)(v.w * c) };
            ((uint2*)(y0 + (size_t)n * F))[qq] = *(uint2*)h;
        }
    }
}

// ---------------------------------------------------------------------------
// Fused gather + MFMA GEMM per layer.
// Block = 512 threads / 8 waves / 64 nodes. Each wave gathers 8 nodes
// (one node at a time, 8 edge-slots x 8 lanes x uint4 — identical inner
// loop to the previous standalone gather), writes the fp16 aggregate row
// directly into the LDS A-tile. One barrier, then 8 waves split the
// 4 row-tiles x 4 col-tiles of a 64x64 @ 64x64 MFMA GEMM with the old
// epilogue (bias, optional relu, optional dinv prescale for next layer).
// Removes the 10 MB agg global round-trip per layer (60 MB total) and
// 2 dispatches per layer; MFMA overlaps other blocks' gather latency.
// ---------------------------------------------------------------------------
template <int RELU, int LAST>
__global__ __launch_bounds__(512, 4) void fused_layer(
        const half_t* __restrict__ y,
        const int* __restrict__ edata, const int* __restrict__ row_ptr,
        const float* __restrict__ dinv,
        const float* __restrict__ W, const float* __restrict__ bias,
        half_t* __restrict__ out_h, float* __restrict__ out_f32) {
    __shared__ __align__(16) half_t Wt[64][72];   // W^T fp16, padded
    __shared__ __align__(16) half_t xt[64][72];   // gathered A tile
    int tid = threadIdx.x;
    for (int i = tid; i < 4096; i += 512) {
        int k = i >> 6, n2 = i & 63;
        Wt[n2][k] = (half_t)W[i];
    }
    int wv = tid >> 6, lane = tid & 63;
    int sub = lane >> 3;        // edge slot 0..7
    int fl  = lane & 7;         // uint4 index within 128 B feature row
    int n0 = blockIdx.x * 64;   // grid = NN/64 exact
    int rbase = wv * 8;         // this wave's 8 rows within the tile
    // one row_ptr load per wave; distribute fences via shfl
    int rp = row_ptr[n0 + rbase + (lane < 9 ? lane : 8)];
    #pragma unroll 1
    for (int i = 0; i < 8; ++i) {
        int n = n0 + rbase + i;
        int p0 = __shfl(rp, i), p1 = __shfl(rp, i + 1);
        uint4 us = ((const uint4*)(y + (size_t)n * F))[fl];   // self row (early)
        float a[8];
        #pragma unroll
        for (int j = 0; j < 8; ++j) a[j] = 0.f;
        int p = p0;
        // full unmasked 32-edge batches (deg > 32 is ~1e-5 of nodes)
        while (p + 32 <= p1) {
            int s[4];
            #pragma unroll
            for (int j = 0; j < 4; ++j) s[j] = edata[p + j * 8 + sub];
            uint4 u[4];
            #pragma unroll
            for (int j = 0; j < 4; ++j)
                u[j] = ((const uint4*)(y + (size_t)s[j] * F))[fl];
            #pragma unroll
            for (int j = 0; j < 4; ++j) {
                float2 f0 = h2f2(u[j].x), f1 = h2f2(u[j].y);
                float2 f2 = h2f2(u[j].z), f3 = h2f2(u[j].w);
                a[0] += f0.x; a[1] += f0.y; a[2] += f1.x; a[3] += f1.y;
                a[4] += f2.x; a[5] += f2.y; a[6] += f3.x; a[7] += f3.y;
            }
            p += 32;
        }
        int rem = p1 - p;           // 0..31
        if (rem > 0) {
            int s[4]; float m[4];
            #pragma unroll
            for (int j = 0; j < 4; ++j) {
                int q = p + j * 8 + sub;
                s[j] = edata[q < p1 ? q : p1 - 1];
                m[j] = (q < p1) ? 1.f : 0.f;
            }
            uint4 u[4];
            u[0] = ((const uint4*)(y + (size_t)s[0] * F))[fl];
            if (rem > 8)  u[1] = ((const uint4*)(y + (size_t)s[1] * F))[fl];
            if (rem > 16) u[2] = ((const uint4*)(y + (size_t)s[2] * F))[fl];
            if (rem > 24) u[3] = ((const uint4*)(y + (size_t)s[3] * F))[fl];
            {
                float2 f0 = h2f2(u[0].x), f1 = h2f2(u[0].y);
                float2 f2 = h2f2(u[0].z), f3 = h2f2(u[0].w);
                a[0] = fmaf(m[0], f0.x, a[0]); a[1] = fmaf(m[0], f0.y, a[1]);
                a[2] = fmaf(m[0], f1.x, a[2]); a[3] = fmaf(m[0], f1.y, a[3]);
                a[4] = fmaf(m[0], f2.x, a[4]); a[5] = fmaf(m[0], f2.y, a[5]);
                a[6] = fmaf(m[0], f3.x, a[6]); a[7] = fmaf(m[0], f3.y, a[7]);
            }
            if (rem > 8) {
                float2 f0 = h2f2(u[1].x), f1 = h2f2(u[1].y);
                float2 f2 = h2f2(u[1].z), f3 = h2f2(u[1].w);
                a[0] = fmaf(m[1], f0.x, a[0]); a[1] = fmaf(m[1], f0.y, a[1]);
                a[2] = fmaf(m[1], f1.x, a[2]); a[3] = fmaf(m[1], f1.y, a[3]);
                a[4] = fmaf(m[1], f2.x, a[4]); a[5] = fmaf(m[1], f2.y, a[5]);
                a[6] = fmaf(m[1], f3.x, a[6]); a[7] = fmaf(m[1], f3.y, a[7]);
            }
            if (rem > 16) {
                float2 f0 = h2f2(u[2].x), f1 = h2f2(u[2].y);
                float2 f2 = h2f2(u[2].z), f3 = h2f2(u[2].w);
                a[0] = fmaf(m[2], f0.x, a[0]); a[1] = fmaf(m[2], f0.y, a[1]);
                a[2] = fmaf(m[2], f1.x, a[2]); a[3] = fmaf(m[2], f1.y, a[3]);
                a[4] = fmaf(m[2], f2.x, a[4]); a[5] = fmaf(m[2], f2.y, a[5]);
                a[6] = fmaf(m[2], f3.x, a[6]); a[7] = fmaf(m[2], f3.y, a[7]);
            }
            if (rem > 24) {
                float2 f0 = h2f2(u[3].x), f1 = h2f2(u[3].y);
                float2 f2 = h2f2(u[3].z), f3 = h2f2(u[3].w);
                a[0] = fmaf(m[3], f0.x, a[0]); a[1] = fmaf(m[3], f0.y, a[1]);
                a[2] = fmaf(m[3], f1.x, a[2]); a[3] = fmaf(m[3], f1.y, a[3]);
                a[4] = fmaf(m[3], f2.x, a[4]); a[5] = fmaf(m[3], f2.y, a[5]);
                a[6] = fmaf(m[3], f3.x, a[6]); a[7] = fmaf(m[3], f3.y, a[7]);
            }
        }
        // reduce 8 slots -> lanes 0..7
        #pragma unroll
        for (int j = 0; j < 8; ++j) {
            a[j] += __shfl_down(a[j], 32);
            a[j] += __shfl_down(a[j], 16);
            a[j] += __shfl_down(a[j], 8);
        }
        if (sub == 0) {
            float dv = rsqrtf((float)(p1 - p0) + 1.f);
            float2 s0 = h2f2(us.x), s1 = h2f2(us.y), s2 = h2f2(us.z), s3 = h2f2(us.w);
            half_t h[8] = {
                (half_t)(dv * (a[0] + s0.x)), (half_t)(dv * (a[1] + s0.y)),
                (half_t)(dv * (a[2] + s1.x)), (half_t)(dv * (a[3] + s1.y)),
                (half_t)(dv * (a[4] + s2.x)), (half_t)(dv * (a[5] + s2.y)),
                (half_t)(dv * (a[6] + s3.x)), (half_t)(dv * (a[7] + s3.y)) };
            *(uint4*)&xt[rbase + i][fl * 8] = *(uint4*)h;
        }
    }
    __syncthreads();
    // MFMA: wave wv -> row-tile (wv&3), col-tiles (wv>>2)*2 + {0,1}
    int m = lane & 15, q = lane >> 4;
    int rt = (wv & 3) * 16;
    int ct0 = (wv >> 2) * 2;
    const half_t* arow = &xt[rt + m][q * 8];
    half8 A0 = *(const half8*)arow;
    half8 A1 = *(const half8*)(arow + 32);
    float dvr[4];
    if (!LAST) {
        #pragma unroll
        for (int r = 0; r < 4; ++r) dvr[r] = dinv[n0 + rt + q * 4 + r];
    }
    #pragma unroll
    for (int c2 = 0; c2 < 2; ++c2) {
        int ct = (ct0 + c2) * 16;
        const half_t* brow = &Wt[ct + m][q * 8];
        half8 B0 = *(const half8*)brow;
        half8 B1 = *(const half8*)(brow + 32);
        f32x4 c = {0.f, 0.f, 0.f, 0.f};
        c = __builtin_amdgcn_mfma_f32_16x16x32_f16(A0, B0, c, 0, 0, 0);
        c = __builtin_amdgcn_mfma_f32_16x16x32_f16(A1, B1, c, 0, 0, 0);
        float bv = bias[ct + m];                   // col = ct*16 + (lane&15)
        #pragma unroll
        for (int r = 0; r < 4; ++r) {
            int row = n0 + rt + q * 4 + r;         // C/D: row = quad*4 + reg
            float v = c[r] + bv;
            if (RELU) v = fmaxf(v, 0.f);
            int col = ct + m;
            if (LAST) out_f32[(size_t)row * F + col] = v;
            else      out_h[(size_t)row * F + col] = (half_t)(v * dvr[r]);
        }
    }
}

extern "C" void kernel_launch(void* const* d_in, const int* in_sizes, int n_in,
                              void* d_out, int out_size, void* d_ws, size_t ws_size,
                              hipStream_t stream) {
    const float* X  = (const float*)d_in[0];
    const int*  idx = (const int*)d_in[1];
    const float* W1 = (const float*)d_in[2];
    const float* b1 = (const float*)d_in[3];
    const float* W2 = (const float*)d_in[4];
    const float* b2 = (const float*)d_in[5];
    const float* W3 = (const float*)d_in[6];
    const float* b3 = (const float*)d_in[7];
    float* out = (float*)d_out;

    char* ws = (char*)d_ws;
    int*    bcur    = (int*)(ws + 256);                 // NB ints
    int*    row_ptr = (int*)(ws + 1024);                // NN+1 ints
    float*  dinv    = (float*)(ws + 321280);            // NN floats
    int*    edata   = (int*)(ws + 641536);              // NE ints (final CSR)
    half_t* ybufA   = (half_t*)(ws + 5761536);          // [NN,64] fp16
    half_t* ybufB   = (half_t*)(ws + 16001536);         // [NN,64] fp16
    int*    ebuf    = (int*)(ws + 26241536);            // NB*CAP ints (7.7 MB)
    // total ws use ~34 MB

    hipMemsetAsync(bcur, 0, NB * sizeof(int), stream);
    partition_kernel<<<PBLK, 512, 0, stream>>>(idx, bcur, ebuf);
    bucket_sort_kernel<<<NB, 1024, 0, stream>>>(bcur, ebuf, X, edata, row_ptr, dinv, ybufA);

    const int fBlocks = NN / 64;      // 1250

    // layer 1: y1 = fp16(dinv*relu(agg(ybufA)@W1+b1)) -> ybufB
    fused_layer<1, 0><<<fBlocks, 512, 0, stream>>>(ybufA, edata, row_ptr, dinv, W1, b1, ybufB, nullptr);
    // layer 2
    fused_layer<1, 0><<<fBlocks, 512, 0, stream>>>(ybufB, edata, row_ptr, dinv, W2, b2, ybufA, nullptr);
    // layer 3: fp32 output, no relu / no scale
    fused_layer<0, 1><<<fBlocks, 512, 0, stream>>>(ybufA, edata, row_ptr, dinv, W3, b3, nullptr, out);
}

// Round 2
// 221.050 us; speedup vs baseline: 1.0347x; 1.0021x over previous
//
#include <hip/hip_runtime.h>
#include <hip/hip_fp16.h>

#define NN 80000
#define NE 1280000
#define F  64
#define BSH 9                        // 512 nodes per bucket
#define NB  157                      // ceil(NN / 512)
#define CAP 12288                    // per-bucket ebuf capacity (avg 8153)
#define EPB 5120                     // edges per partition block (128 B runs)
#define EPT 10                       // EPB / 512
#define PBLK (NE / EPB)              // 250

typedef _Float16 half_t;
typedef _Float16 half8 __attribute__((ext_vector_type(8)));
typedef float f32x4 __attribute__((ext_vector_type(4)));
typedef unsigned int uint_t;

__device__ __forceinline__ float2 h2f2(uint_t u) {
    __half2 h = *(__half2*)&u;
    return __half22float2(h);
}

__device__ __forceinline__ int ld_src(const int* __restrict__ idx, int e, int is64) {
    return is64 ? idx[2 * e] : idx[e];
}
__device__ __forceinline__ int ld_dst(const int* __restrict__ idx, int e, int is64) {
    return is64 ? idx[2 * NE + 2 * e] : idx[NE + e];
}

// ---------------------------------------------------------------------------
// Pass 1 (512 threads): partition edges into NB dst-buckets via LDS staging
// (cache-granular global writes, ~32-edge/128 B runs).
// ebuf[b*CAP + j] = (dstoff<<17) | src. Inline int64-vs-int32 sniff.
// ---------------------------------------------------------------------------
__global__ __launch_bounds__(512) void partition_kernel(
        const int* __restrict__ idx,
        int* __restrict__ bcur, int* __restrict__ ebuf) {
    __shared__ int cnt[NB];
    __shared__ int lbase[NB];
    __shared__ int gbase[NB];
    __shared__ int lds_val[EPB];
    __shared__ int lds_gaddr[EPB];
    __shared__ int is64_s;
    int tid = threadIdx.x;
    if (tid == 0) is64_s = 1;
    if (tid < NB) cnt[tid] = 0;
    __syncthreads();
    if (idx[2 * tid + 1] != 0) is64_s = 0;   // benign same-value race
    __syncthreads();
    int is64 = is64_s;
    int e0 = blockIdx.x * EPB;
    int val[EPT], br[EPT];
    #pragma unroll
    for (int j = 0; j < EPT; ++j) {
        int e = e0 + j * 512 + tid;
        int s = ld_src(idx, e, is64);
        int d = ld_dst(idx, e, is64);
        int b = d >> BSH;
        val[j] = ((d & ((1 << BSH) - 1)) << 17) | s;
        int r = atomicAdd(&cnt[b], 1);       // rank within (block, bucket)
        br[j] = (b << 13) | r;               // r < 5120 < 2^13
    }
    __syncthreads();
    if (tid < 64) {
        int carry = 0;
        for (int base = 0; base < NB; base += 64) {
            int i2 = base + tid;
            int v = (i2 < NB) ? cnt[i2] : 0;
            int incl = v;
            #pragma unroll
            for (int d2 = 1; d2 < 64; d2 <<= 1) {
                int t = __shfl_up(incl, d2, 64);
                if (tid >= d2) incl += t;
            }
            if (i2 < NB) lbase[i2] = carry + incl - v;
            carry += __shfl(incl, 63);
        }
    } else if (tid - 64 < NB) {
        int b = tid - 64;
        gbase[b] = atomicAdd(&bcur[b], cnt[b]);
    }
    __syncthreads();
    #pragma unroll
    for (int j = 0; j < EPT; ++j) {
        int b = br[j] >> 13, r = br[j] & 8191;
        int slot = lbase[b] + r;
        int g = gbase[b] + r;
        lds_val[slot]   = val[j];
        lds_gaddr[slot] = (g < CAP) ? (b * CAP + g) : -1;   // overflow guard
    }
    __syncthreads();
    for (int i = tid; i < EPB; i += 512) {
        int a = lds_gaddr[i];
        if (a >= 0) ebuf[a] = lds_val[i];    // ~32-edge (128 B) contiguous runs
    }
}

// ---------------------------------------------------------------------------
// Pass 2 (1024 threads): per-bucket LDS counting sort -> final CSR edata +
// row_ptr + dinv, with prescale folded in (y0 = fp16(X * dinv)).
// ---------------------------------------------------------------------------
__global__ __launch_bounds__(1024) void bucket_sort_kernel(
        const int* __restrict__ bcur, const int* __restrict__ ebuf,
        const float* __restrict__ X,
        int* __restrict__ edata, int* __restrict__ row_ptr,
        float* __restrict__ dinv, half_t* __restrict__ y0) {
    __shared__ int cnt[512];
    __shared__ int off[512];
    __shared__ int lds_out[CAP];
    __shared__ int ebase_s;
    int b = blockIdx.x, tid = threadIdx.x;
    if (tid < 512) cnt[tid] = 0;
    if (tid < 64) {        // ebase = sum of min(bcur[j],CAP) for j<b
        int carry = 0;
        for (int base = 0; base < NB; base += 64) {
            int i2 = base + tid;
            int v = (i2 < NB) ? min(bcur[i2], CAP) : 0;
            int incl = v;
            #pragma unroll
            for (int d2 = 1; d2 < 64; d2 <<= 1) {
                int t = __shfl_up(incl, d2, 64);
                if (tid >= d2) incl += t;
            }
            if (i2 == b) ebase_s = carry + incl - v;
            carry += __shfl(incl, 63);
        }
    }
    __syncthreads();
    int bcnt = min(bcur[b], CAP);
    int ebase = ebase_s;
    const int* src = ebuf + b * CAP;
    for (int i = tid; i < bcnt; i += 1024)
        atomicAdd(&cnt[src[i] >> 17], 1);
    __syncthreads();
    if (tid < 64) {        // exclusive scan of 512 counters
        int carry = 0;
        #pragma unroll
        for (int base = 0; base < 512; base += 64) {
            int v = cnt[base + tid];
            int incl = v;
            #pragma unroll
            for (int d2 = 1; d2 < 64; d2 <<= 1) {
                int t = __shfl_up(incl, d2, 64);
                if (tid >= d2) incl += t;
            }
            off[base + tid] = carry + incl - v;
            carry += __shfl(incl, 63);
        }
    }
    __syncthreads();
    int n0 = b << BSH;
    if (tid < 512) {
        int n = n0 + tid;
        if (n < NN) {
            row_ptr[n] = ebase + off[tid];
            dinv[n] = rsqrtf((float)cnt[tid] + 1.f);
        } else if (n == NN) {
            row_ptr[NN] = ebase + off[tid];
        }
    }
    __syncthreads();
    for (int i = tid; i < bcnt; i += 1024) {
        int w = src[i];
        int pos = atomicAdd(&off[w >> 17], 1);
        lds_out[pos] = w & 0x1FFFF;
    }
    __syncthreads();
    for (int i = tid; i < bcnt; i += 1024)
        edata[ebase + i] = lds_out[i];
    // folded prescale: y0 = fp16(X * dinv) for this bucket's 512 rows.
    for (int i = tid; i < (512 << 4); i += 1024) {
        int r = i >> 4, qq = i & 15;
        int n = n0 + r;
        if (n < NN) {
            float c = rsqrtf((float)cnt[r] + 1.f);
            float4 v = ((const float4*)(X + (size_t)n * F))[qq];
            half_t h[4] = { (half_t)(v.x * c), (half_t)(v.y * c),
                            (half_t)(v.z * c), (half_t)(v.w * c) };
            ((uint2*)(y0 + (size_t)n * F))[qq] = *(uint2*)h;
        }
    }
}

// --------------------------- gather helpers --------------------------------
__device__ __forceinline__ uint4 ldrow(const half_t* __restrict__ y, int s, int fl) {
    return ((const uint4*)(y + (size_t)s * F))[fl];
}

__device__ __forceinline__ void acc8(float* a, const uint4& u, float m) {
    float2 f0 = h2f2(u.x), f1 = h2f2(u.y);
    float2 f2 = h2f2(u.z), f3 = h2f2(u.w);
    a[0] = fmaf(m, f0.x, a[0]); a[1] = fmaf(m, f0.y, a[1]);
    a[2] = fmaf(m, f1.x, a[2]); a[3] = fmaf(m, f1.y, a[3]);
    a[4] = fmaf(m, f2.x, a[4]); a[5] = fmaf(m, f2.y, a[5]);
    a[6] = fmaf(m, f3.x, a[6]); a[7] = fmaf(m, f3.y, a[7]);
}

// full unmasked 32-edge batch (deg > 32 is ~3e-5 of nodes; wave-uniform branch)
__device__ __forceinline__ void batch32(float* a, const half_t* __restrict__ y,
        const int* __restrict__ edata, int p, int sub, int fl) {
    int s[4];
    #pragma unroll
    for (int j = 0; j < 4; ++j) s[j] = edata[p + j * 8 + sub];
    uint4 u[4];
    #pragma unroll
    for (int j = 0; j < 4; ++j) u[j] = ldrow(y, s[j], fl);
    #pragma unroll
    for (int j = 0; j < 4; ++j) acc8(a, u[j], 1.f);
}

// ---------------------------------------------------------------------------
// Fused gather + MFMA GEMM per layer, 2-node-interleaved gather.
// Block = 512 threads / 8 waves / 64 nodes; each wave gathers 8 nodes in
// 4 PAIRS. The tail (rem 0..31) is BRANCH-FREE: all 4 clamped row loads are
// always issued with masked fmaf (clamped dup slots hit one extra 128 B
// line per node, L1-resident). Both nodes' 8 edata + 8 row + 2 self loads
// sit in one basic block -> scheduler issues ~18 loads in flight, halving
// the number of serial latency chains per wave (8 -> 4).
// ---------------------------------------------------------------------------
template <int RELU, int LAST>
__global__ __launch_bounds__(512, 4) void fused_layer(
        const half_t* __restrict__ y,
        const int* __restrict__ edata, const int* __restrict__ row_ptr,
        const float* __restrict__ dinv,
        const float* __restrict__ W, const float* __restrict__ bias,
        half_t* __restrict__ out_h, float* __restrict__ out_f32) {
    __shared__ __align__(16) half_t Wt[64][72];   // W^T fp16, padded
    __shared__ __align__(16) half_t xt[64][72];   // gathered A tile
    int tid = threadIdx.x;
    for (int i = tid; i < 4096; i += 512) {
        int k = i >> 6, n2 = i & 63;
        Wt[n2][k] = (half_t)W[i];
    }
    int wv = tid >> 6, lane = tid & 63;
    int sub = lane >> 3;        // edge slot 0..7
    int fl  = lane & 7;         // uint4 index within 128 B feature row
    int n0 = blockIdx.x * 64;   // grid = NN/64 exact
    int rbase = wv * 8;         // this wave's 8 rows within the tile
    // one row_ptr load per wave; distribute fences via shfl
    int rp = row_ptr[n0 + rbase + (lane < 9 ? lane : 8)];
    #pragma unroll 1
    for (int i = 0; i < 8; i += 2) {
        int nA = n0 + rbase + i;
        int pA0 = __shfl(rp, i), pA1 = __shfl(rp, i + 1), pB1 = __shfl(rp, i + 2);
        int pB0 = pA1;
        uint4 usA = ldrow(y, nA, fl);       // self rows, issued early
        uint4 usB = ldrow(y, nA + 1, fl);
        float aA[8], aB[8];
        #pragma unroll
        for (int j = 0; j < 8; ++j) { aA[j] = 0.f; aB[j] = 0.f; }
        int pA = pA0, pB = pB0;
        while (pA + 32 <= pA1) { batch32(aA, y, edata, pA, sub, fl); pA += 32; }
        while (pB + 32 <= pB1) { batch32(aB, y, edata, pB, sub, fl); pB += 32; }
        // branch-free masked tails for BOTH nodes (single basic block)
        int sA[4], sB[4]; float mA[4], mB[4];
        #pragma unroll
        for (int j = 0; j < 4; ++j) {
            int qA = pA + j * 8 + sub;
            int cA = qA < pA1 ? qA : pA1 - 1;  cA = cA > 0 ? cA : 0;
            sA[j] = edata[cA];  mA[j] = (qA < pA1) ? 1.f : 0.f;
            int qB = pB + j * 8 + sub;
            int cB = qB < pB1 ? qB : pB1 - 1;  cB = cB > 0 ? cB : 0;
            sB[j] = edata[cB];  mB[j] = (qB < pB1) ? 1.f : 0.f;
        }
        uint4 uA[4], uB[4];
        #pragma unroll
        for (int j = 0; j < 4; ++j) { uA[j] = ldrow(y, sA[j], fl);
                                      uB[j] = ldrow(y, sB[j], fl); }
        #pragma unroll
        for (int j = 0; j < 4; ++j) { acc8(aA, uA[j], mA[j]);
                                      acc8(aB, uB[j], mB[j]); }
        // reduce 8 slots -> lanes 0..7 (both nodes)
        #pragma unroll
        for (int j = 0; j < 8; ++j) {
            aA[j] += __shfl_down(aA[j], 32);
            aA[j] += __shfl_down(aA[j], 16);
            aA[j] += __shfl_down(aA[j], 8);
            aB[j] += __shfl_down(aB[j], 32);
            aB[j] += __shfl_down(aB[j], 16);
            aB[j] += __shfl_down(aB[j], 8);
        }
        if (sub == 0) {
            float dvA = rsqrtf((float)(pA1 - pA0) + 1.f);
            float2 s0 = h2f2(usA.x), s1 = h2f2(usA.y), s2 = h2f2(usA.z), s3 = h2f2(usA.w);
            half_t h[8] = {
                (half_t)(dvA * (aA[0] + s0.x)), (half_t)(dvA * (aA[1] + s0.y)),
                (half_t)(dvA * (aA[2] + s1.x)), (half_t)(dvA * (aA[3] + s1.y)),
                (half_t)(dvA * (aA[4] + s2.x)), (half_t)(dvA * (aA[5] + s2.y)),
                (half_t)(dvA * (aA[6] + s3.x)), (half_t)(dvA * (aA[7] + s3.y)) };
            *(uint4*)&xt[rbase + i][fl * 8] = *(uint4*)h;
            float dvB = rsqrtf((float)(pB1 - pB0) + 1.f);
            float2 t0 = h2f2(usB.x), t1 = h2f2(usB.y), t2 = h2f2(usB.z), t3 = h2f2(usB.w);
            half_t g[8] = {
                (half_t)(dvB * (aB[0] + t0.x)), (half_t)(dvB * (aB[1] + t0.y)),
                (half_t)(dvB * (aB[2] + t1.x)), (half_t)(dvB * (aB[3] + t1.y)),
                (half_t)(dvB * (aB[4] + t2.x)), (half_t)(dvB * (aB[5] + t2.y)),
                (half_t)(dvB * (aB[6] + t3.x)), (half_t)(dvB * (aB[7] + t3.y)) };
            *(uint4*)&xt[rbase + i + 1][fl * 8] = *(uint4*)g;
        }
    }
    __syncthreads();
    // MFMA: wave wv -> row-tile (wv&3), col-tiles (wv>>2)*2 + {0,1}
    int m = lane & 15, q = lane >> 4;
    int rt = (wv & 3) * 16;
    int ct0 = (wv >> 2) * 2;
    const half_t* arow = &xt[rt + m][q * 8];
    half8 A0 = *(const half8*)arow;
    half8 A1 = *(const half8*)(arow + 32);
    float dvr[4];
    if (!LAST) {
        #pragma unroll
        for (int r = 0; r < 4; ++r) dvr[r] = dinv[n0 + rt + q * 4 + r];
    }
    #pragma unroll
    for (int c2 = 0; c2 < 2; ++c2) {
        int ct = (ct0 + c2) * 16;
        const half_t* brow = &Wt[ct + m][q * 8];
        half8 B0 = *(const half8*)brow;
        half8 B1 = *(const half8*)(brow + 32);
        f32x4 c = {0.f, 0.f, 0.f, 0.f};
        c = __builtin_amdgcn_mfma_f32_16x16x32_f16(A0, B0, c, 0, 0, 0);
        c = __builtin_amdgcn_mfma_f32_16x16x32_f16(A1, B1, c, 0, 0, 0);
        float bv = bias[ct + m];                   // col = ct*16 + (lane&15)
        #pragma unroll
        for (int r = 0; r < 4; ++r) {
            int row = n0 + rt + q * 4 + r;         // C/D: row = quad*4 + reg
            float v = c[r] + bv;
            if (RELU) v = fmaxf(v, 0.f);
            int col = ct + m;
            if (LAST) out_f32[(size_t)row * F + col] = v;
            else      out_h[(size_t)row * F + col] = (half_t)(v * dvr[r]);
        }
    }
}

extern "C" void kernel_launch(void* const* d_in, const int* in_sizes, int n_in,
                              void* d_out, int out_size, void* d_ws, size_t ws_size,
                              hipStream_t stream) {
    const float* X  = (const float*)d_in[0];
    const int*  idx = (const int*)d_in[1];
    const float* W1 = (const float*)d_in[2];
    const float* b1 = (const float*)d_in[3];
    const float* W2 = (const float*)d_in[4];
    const float* b2 = (const float*)d_in[5];
    const float* W3 = (const float*)d_in[6];
    const float* b3 = (const float*)d_in[7];
    float* out = (float*)d_out;

    char* ws = (char*)d_ws;
    int*    bcur    = (int*)(ws + 256);                 // NB ints
    int*    row_ptr = (int*)(ws + 1024);                // NN+1 ints
    float*  dinv    = (float*)(ws + 321280);            // NN floats
    int*    edata   = (int*)(ws + 641536);              // NE ints (final CSR)
    half_t* ybufA   = (half_t*)(ws + 5761536);          // [NN,64] fp16
    half_t* ybufB   = (half_t*)(ws + 16001536);         // [NN,64] fp16
    int*    ebuf    = (int*)(ws + 26241536);            // NB*CAP ints (7.7 MB)
    // total ws use ~34 MB

    hipMemsetAsync(bcur, 0, NB * sizeof(int), stream);
    partition_kernel<<<PBLK, 512, 0, stream>>>(idx, bcur, ebuf);
    bucket_sort_kernel<<<NB, 1024, 0, stream>>>(bcur, ebuf, X, edata, row_ptr, dinv, ybufA);

    const int fBlocks = NN / 64;      // 1250

    // layer 1: y1 = fp16(dinv*relu(agg(ybufA)@W1+b1)) -> ybufB
    fused_layer<1, 0><<<fBlocks, 512, 0, stream>>>(ybufA, edata, row_ptr, dinv, W1, b1, ybufB, nullptr);
    // layer 2
    fused_layer<1, 0><<<fBlocks, 512, 0, stream>>>(ybufB, edata, row_ptr, dinv, W2, b2, ybufA, nullptr);
    // layer 3: fp32 output, no relu / no scale
    fused_layer<0, 1><<<fBlocks, 512, 0, stream>>>(ybufA, edata, row_ptr, dinv, W3, b3, nullptr, out);
}